// Round 1
// baseline (77.059 us; speedup 1.0000x reference)
//
#include <hip/hip_runtime.h>
#include <math.h>

#define BATCH 2
#define NPTS  1024
#define NC    32
#define DIN   8
#define DOUT  8
#define ATILE 64                          // a's per block (4 waves x 16)
#define NCHUNK 64                         // b-splits
#define BPW   (NPTS / NCHUNK)             // 16 b's per block
#define OUT_ELEMS (BATCH * NPTS * DOUT)   // 16384
#define NE4   (OUT_ELEMS / 4)             // 4096
#define LOG2E 1.4426950408889634f
#define G_BYTES ((size_t)BATCH * NPTS * 64 * 16)   // 2 MB of half8 B-frags

typedef _Float16 half8 __attribute__((ext_vector_type(8)));
typedef __fp16   fp16x2 __attribute__((ext_vector_type(2)));
typedef float    floatx4 __attribute__((ext_vector_type(4)));

#if __has_builtin(__builtin_amdgcn_exp2f)
#define EXP2F(x) __builtin_amdgcn_exp2f(x)
#else
#define EXP2F(x) exp2f(x)
#endif

// ---------------------------------------------------------------------------
// g_kernel (unchanged, R11-verified): one-time build of B-frags in ws.
// Slot layout per b: slot = oct*16 + i (i<8) holds G[c=oct*8+j][i], j=0..7;
// slots with (slot&8) are the n>=8 half of the B operand -> zero.
// ---------------------------------------------------------------------------
__global__ __launch_bounds__(256) void g_kernel(
        const float* __restrict__ feat,
        const float* __restrict__ W,
        half8*       __restrict__ gws) {
    const int e    = blockIdx.x * 256 + threadIdx.x;  // < BATCH*NPTS*64
    const int slot = e & 63;
    const int zb   = e >> 6;
    half8 gv = {};
    if (!(slot & 8)) {
        const int i   = slot & 7;
        const int oct = slot >> 4;
        const float* f = feat + (size_t)zb * DIN;
        const float4 f0 = *(const float4*)f;
        const float4 f1 = *(const float4*)(f + 4);
#pragma unroll
        for (int j = 0; j < 8; ++j) {
            const float* wr = W + ((oct * 8 + j) * DOUT + i) * DIN;
            const float4 wa = *(const float4*)wr;
            const float4 wb = *(const float4*)(wr + 4);
            float s = fmaf(wa.x, f0.x,
                      fmaf(wa.y, f0.y,
                      fmaf(wa.z, f0.z,
                      fmaf(wa.w, f0.w,
                      fmaf(wb.x, f1.x,
                      fmaf(wb.y, f1.y,
                      fmaf(wb.z, f1.z,
                             wb.w * f1.w)))))));
            gv[j] = (_Float16)s;
        }
    }
    gws[e] = gv;
}

// ---------------------------------------------------------------------------
// conv_mfma v5 — attack LATENCY, not issue (R12 post-mortem: trans cut 9->4
// was null => conv is not issue-bound; 33us vs ~5us issue model => stalls).
// Changes vs v4 (math + layouts byte-identical):
//  * B-frags staged once per block into LDS (chunk = 16 KB contiguous in gws),
//    MFMA feeds from ds_read_b128 (~120cyc, pipelineable) instead of 16
//    in-flight global_load_dwordx4 (64 VGPR payload + 200-400cyc latency).
//  * unroll 16 -> 4: shrinks live set; geo reads stay wave-uniform s_loads.
//  * __launch_bounds__(256,8): target <=64 VGPR => 8 waves/SIMD (was 4 at
//    the 128-VGPR cap), 8 blocks/CU, LDS 8x16KB=128KB < 160KB.
// Exp recurrence unchanged (R12-verified numerics, NaN/underflow proof holds).
// ---------------------------------------------------------------------------
__global__ __launch_bounds__(256, 8) void conv_mfma(
        const float* __restrict__ geo,
        const half8* __restrict__ gws,
        float*       __restrict__ partial) {  // [NCHUNK][BATCH*NPTS][DOUT]
    const int t     = threadIdx.x;
    const int bid   = blockIdx.x;
    const int chunk = bid & (NCHUNK - 1);
    const int atile = (bid >> 6) & 15;
    const int z     = bid >> 10;

    const int b0 = chunk * BPW;
    const float* geoz = geo + (size_t)z * NPTS * 3;
    const float* bge  = geoz + b0 * 3;         // wave-uniform base

    const int lane = t & 63;
    const int wv   = t >> 6;
    const int m    = lane & 15;
    const int quad = lane >> 4;
    const int a0   = atile * ATILE + wv * 16;
    const int a    = a0 + m;

    // ---- stage this chunk's B-frags: 16 b x 64 slots x 16B = 16 KB ----
    __shared__ half8 ldsG[BPW * 64];
    {
        const float4* src = (const float4*)(gws + (size_t)(z * NPTS + b0) * 64);
        float4* dst = (float4*)ldsG;
#pragma unroll
        for (int p = 0; p < 4; ++p)
            dst[p * 256 + t] = src[p * 256 + t];
    }

    const float ax = geoz[a * 3 + 0];
    const float ay = geoz[a * 3 + 1];
    const float az = geoz[a * 3 + 2];
    const float c0   = (float)(quad * 8);
    const float invw = (float)(NC - 1) / 3.5f;
    const float K2   = 0.13533528324f;         // exp(-2)
    const float K8   = 3.35462627903e-4f;      // exp(-8)

    floatx4 acc0 = {0.f, 0.f, 0.f, 0.f};
    floatx4 acc1 = {0.f, 0.f, 0.f, 0.f};

    __syncthreads();

#pragma unroll 4
    for (int b = 0; b < BPW; ++b) {
        // wave-uniform geo (uniform address -> s_load regardless of unroll)
        const float bx = bge[b * 3 + 0];
        const float by = bge[b * 3 + 1];
        const float bz = bge[b * 3 + 2];
        const float dx = bx - ax, dy = by - ay, dz = bz - az;
        const float u  = sqrtf(fmaf(dx, dx, fmaf(dy, dy, fmaf(dz, dz, 1e-12f)))) * invw;
        const float tc = fminf(u - c0, 11.0f);
        // seeds + ratios
        const float e0 = EXP2F((tc * tc) * (-LOG2E));
        const float t4 = tc - 4.0f;
        const float e4 = EXP2F((t4 * t4) * (-LOG2E));
        const float r0 = EXP2F(fmaf(2.0f * LOG2E, tc, -LOG2E));   // exp(2tc-1)
        const float r4 = r0 * K8;                                  // exp(2t4-1)
        // chains (<=3 muls from each seed)
        const float e1 = e0 * r0;  const float r1 = r0 * K2;
        const float e2 = e1 * r1;  const float r2 = r1 * K2;
        const float e3 = e2 * r2;
        const float e5 = e4 * r4;  const float r5 = r4 * K2;
        const float e6 = e5 * r5;  const float r6 = r5 * K2;
        const float e7 = e6 * r6;
        union { half8 v; fp16x2 h[4]; } af;
        af.h[0] = __builtin_amdgcn_cvt_pkrtz(e0, e1);
        af.h[1] = __builtin_amdgcn_cvt_pkrtz(e2, e3);
        af.h[2] = __builtin_amdgcn_cvt_pkrtz(e4, e5);
        af.h[3] = __builtin_amdgcn_cvt_pkrtz(e6, e7);
        const half8 bfrg = ldsG[b * 64 + lane];    // ds_read_b128, conflict-free
        if (b & 1)
            acc1 = __builtin_amdgcn_mfma_f32_16x16x32_f16(af.v, bfrg, acc1, 0, 0, 0);
        else
            acc0 = __builtin_amdgcn_mfma_f32_16x16x32_f16(af.v, bfrg, acc0, 0, 0, 0);
    }

    // ---- epilogue: D col = i (lane&15, keep <8), row = quad*4 + reg ----
    if (m < 8) {
        float* pp = partial + (size_t)chunk * OUT_ELEMS
                  + ((size_t)(z * NPTS + a0 + quad * 4)) * DOUT + m;
#pragma unroll
        for (int r = 0; r < 4; ++r)
            pp[r * DOUT] = acc0[r] + acc1[r];
    }
}

// ---------------------------------------------------------------------------
// reduce_partials: 256 blocks, 16 f4-elems x 16 chunk-groups; each thread
// sums NCH/16 independent loads, then 16-way LDS reduction.
// ---------------------------------------------------------------------------
template <int NCH>
__global__ __launch_bounds__(256) void reduce_partials(
        const float* __restrict__ partial,
        const int*   __restrict__ n_norm,
        float*       __restrict__ out) {
    const int tx = threadIdx.x & 15;
    const int ty = threadIdx.x >> 4;
    const int e4 = blockIdx.x * 16 + tx;
    const float4* p = (const float4*)partial;

    float4 s = make_float4(0.f, 0.f, 0.f, 0.f);
#pragma unroll
    for (int j = 0; j < NCH / 16; ++j) {
        float4 v = p[(size_t)(j * 16 + ty) * NE4 + e4];
        s.x += v.x; s.y += v.y; s.z += v.z; s.w += v.w;
    }

    __shared__ float4 red[16][16];
    red[ty][tx] = s;
    __syncthreads();

    if (ty == 0) {
        float4 tot = red[0][tx];
#pragma unroll
        for (int j = 1; j < 16; ++j) {
            float4 v = red[j][tx];
            tot.x += v.x; tot.y += v.y; tot.z += v.z; tot.w += v.w;
        }
        const float scale = 1.0f / sqrtf((float)n_norm[0]);
        ((float4*)out)[e4] = make_float4(tot.x * scale, tot.y * scale,
                                         tot.z * scale, tot.w * scale);
    }
}

// ---------------------------------------------------------------------------
extern "C" void kernel_launch(void* const* d_in, const int* in_sizes, int n_in,
                              void* d_out, int out_size, void* d_ws, size_t ws_size,
                              hipStream_t stream) {
    const float* feat   = (const float*)d_in[0];   // [2,1024,8]
    const float* geo    = (const float*)d_in[1];   // [2,1024,3]
    const float* W      = (const float*)d_in[2];   // [32,8,8]
    const int*   n_norm = (const int*)  d_in[3];   // scalar 1024
    float* out = (float*)d_out;                    // [2,1024,8]

    half8* gws     = (half8*)d_ws;                              // 2 MB
    float* partial = (float*)((char*)d_ws + G_BYTES);           // 4 MB

    g_kernel<<<(BATCH * NPTS * 64) / 256, 256, 0, stream>>>(feat, W, gws);
    conv_mfma<<<BATCH * 16 * NCHUNK, 256, 0, stream>>>(geo, gws, partial);
    reduce_partials<NCHUNK><<<NE4 / 16, 256, 0, stream>>>(partial, n_norm, out);
}

// Round 2
// 74.320 us; speedup vs baseline: 1.0369x; 1.0369x over previous
//
#include <hip/hip_runtime.h>
#include <math.h>

#define BATCH 2
#define NPTS  1024
#define NC    32
#define DIN   8
#define DOUT  8
#define ATILE 64                          // a's per block (4 waves x 16)
#define NCHUNK 32                         // b-splits (was 64)
#define BPW   (NPTS / NCHUNK)             // 32 b's per block
#define OUT_ELEMS (BATCH * NPTS * DOUT)   // 16384
#define LOG2E 1.4426950408889634f
#define G_BYTES ((size_t)BATCH * NPTS * 64 * 16)   // 2 MB of half8 B-frags

typedef _Float16 half8 __attribute__((ext_vector_type(8)));
typedef __fp16   fp16x2 __attribute__((ext_vector_type(2)));
typedef float    floatx4 __attribute__((ext_vector_type(4)));

#if __has_builtin(__builtin_amdgcn_exp2f)
#define EXP2F(x) __builtin_amdgcn_exp2f(x)
#else
#define EXP2F(x) exp2f(x)
#endif

// ---------------------------------------------------------------------------
// g_kernel v2: one-time build of B-frags in ws (layout identical to R11).
// New in v6: (a) folds 1/sqrt(n_norm) into G (device-side read, so the
// final scale pass disappears); (b) zeroes `out` (first 64 blocks' worth of
// threads) so conv can accumulate with atomics -> reduce kernel removed.
// Precision: scale folded pre-f16-quantization changes only the exponent of
// G values (fp16 is scale-invariant in relative error), accumulate stays f32.
// ---------------------------------------------------------------------------
__global__ __launch_bounds__(256) void g_kernel(
        const float* __restrict__ feat,
        const float* __restrict__ W,
        const int*   __restrict__ n_norm,
        half8*       __restrict__ gws,
        float*       __restrict__ out) {
    const int e    = blockIdx.x * 256 + threadIdx.x;  // < BATCH*NPTS*64
    if (e < OUT_ELEMS) out[e] = 0.f;                  // zero-init for atomics
    const int slot = e & 63;
    const int zb   = e >> 6;
    const float scale = 1.0f / sqrtf((float)n_norm[0]);
    half8 gv = {};
    if (!(slot & 8)) {
        const int i   = slot & 7;
        const int oct = slot >> 4;
        const float* f = feat + (size_t)zb * DIN;
        const float4 f0 = *(const float4*)f;
        const float4 f1 = *(const float4*)(f + 4);
#pragma unroll
        for (int j = 0; j < 8; ++j) {
            const float* wr = W + ((oct * 8 + j) * DOUT + i) * DIN;
            const float4 wa = *(const float4*)wr;
            const float4 wb = *(const float4*)(wr + 4);
            float s = fmaf(wa.x, f0.x,
                      fmaf(wa.y, f0.y,
                      fmaf(wa.z, f0.z,
                      fmaf(wa.w, f0.w,
                      fmaf(wb.x, f1.x,
                      fmaf(wb.y, f1.y,
                      fmaf(wb.z, f1.z,
                             wb.w * f1.w)))))));
            gv[j] = (_Float16)(s * scale);
        }
    }
    gws[e] = gv;
}

// ---------------------------------------------------------------------------
// conv_mfma v6 — attack DISPATCH/EPILOGUE STRUCTURE (R12+R13 post-mortem:
// trans-cut null AND lds+occupancy null => inner loop is neither issue- nor
// load-latency-bound; remaining time must be in the 4-dispatch structure,
// the 4MB partial round-trip, and short-loop (16-iter) prologue/epilogue
// amortization).
// Changes vs v5 (inner-loop math byte-identical):
//  * direct accumulation into `out` via global_atomic_add_f32 (32 adds per
//    address, overlapped with compute) -> partial tensor + reduce kernel gone.
//  * NCHUNK 32 (BPW=32): 1024 blocks = 4/CU, LDS 4x32KB=128KB; prologue/
//    epilogue amortized over 2x the MFMAs, atomic depth halved vs NCHUNK=64.
// Exp recurrence unchanged (R12-verified numerics, NaN/underflow proof holds).
// ---------------------------------------------------------------------------
__global__ __launch_bounds__(256, 4) void conv_mfma(
        const float* __restrict__ geo,
        const half8* __restrict__ gws,
        float*       __restrict__ out) {   // [BATCH*NPTS][DOUT], pre-zeroed
    const int t     = threadIdx.x;
    const int bid   = blockIdx.x;
    const int chunk = bid & (NCHUNK - 1);
    const int atile = (bid >> 5) & 15;
    const int z     = bid >> 9;

    const int b0 = chunk * BPW;
    const float* geoz = geo + (size_t)z * NPTS * 3;
    const float* bge  = geoz + b0 * 3;         // wave-uniform base

    const int lane = t & 63;
    const int wv   = t >> 6;
    const int m    = lane & 15;
    const int quad = lane >> 4;
    const int a0   = atile * ATILE + wv * 16;
    const int a    = a0 + m;

    // ---- stage this chunk's B-frags: 32 b x 64 slots x 16B = 32 KB ----
    __shared__ half8 ldsG[BPW * 64];
    {
        const float4* src = (const float4*)(gws + (size_t)(z * NPTS + b0) * 64);
        float4* dst = (float4*)ldsG;
#pragma unroll
        for (int p = 0; p < 8; ++p)
            dst[p * 256 + t] = src[p * 256 + t];
    }

    const float ax = geoz[a * 3 + 0];
    const float ay = geoz[a * 3 + 1];
    const float az = geoz[a * 3 + 2];
    const float c0   = (float)(quad * 8);
    const float invw = (float)(NC - 1) / 3.5f;
    const float K2   = 0.13533528324f;         // exp(-2)
    const float K8   = 3.35462627903e-4f;      // exp(-8)

    floatx4 acc0 = {0.f, 0.f, 0.f, 0.f};
    floatx4 acc1 = {0.f, 0.f, 0.f, 0.f};

    __syncthreads();

#pragma unroll 4
    for (int b = 0; b < BPW; ++b) {
        // wave-uniform geo (uniform address -> s_load)
        const float bx = bge[b * 3 + 0];
        const float by = bge[b * 3 + 1];
        const float bz = bge[b * 3 + 2];
        const float dx = bx - ax, dy = by - ay, dz = bz - az;
        const float u  = sqrtf(fmaf(dx, dx, fmaf(dy, dy, fmaf(dz, dz, 1e-12f)))) * invw;
        const float tc = fminf(u - c0, 11.0f);
        // seeds + ratios
        const float e0 = EXP2F((tc * tc) * (-LOG2E));
        const float t4 = tc - 4.0f;
        const float e4 = EXP2F((t4 * t4) * (-LOG2E));
        const float r0 = EXP2F(fmaf(2.0f * LOG2E, tc, -LOG2E));   // exp(2tc-1)
        const float r4 = r0 * K8;                                  // exp(2t4-1)
        // chains (<=3 muls from each seed)
        const float e1 = e0 * r0;  const float r1 = r0 * K2;
        const float e2 = e1 * r1;  const float r2 = r1 * K2;
        const float e3 = e2 * r2;
        const float e5 = e4 * r4;  const float r5 = r4 * K2;
        const float e6 = e5 * r5;  const float r6 = r5 * K2;
        const float e7 = e6 * r6;
        union { half8 v; fp16x2 h[4]; } af;
        af.h[0] = __builtin_amdgcn_cvt_pkrtz(e0, e1);
        af.h[1] = __builtin_amdgcn_cvt_pkrtz(e2, e3);
        af.h[2] = __builtin_amdgcn_cvt_pkrtz(e4, e5);
        af.h[3] = __builtin_amdgcn_cvt_pkrtz(e6, e7);
        const half8 bfrg = ldsG[b * 64 + lane];    // ds_read_b128, conflict-free
        if (b & 1)
            acc1 = __builtin_amdgcn_mfma_f32_16x16x32_f16(af.v, bfrg, acc1, 0, 0, 0);
        else
            acc0 = __builtin_amdgcn_mfma_f32_16x16x32_f16(af.v, bfrg, acc0, 0, 0, 0);
    }

    // ---- epilogue: D col = i (lane&15, keep <8), row = quad*4 + reg ----
    // Direct atomic accumulate into out (scale already folded into G).
    if (m < 8) {
        float* pp = out + ((size_t)(z * NPTS + a0 + quad * 4)) * DOUT + m;
#pragma unroll
        for (int r = 0; r < 4; ++r)
            atomicAdd(pp + r * DOUT, acc0[r] + acc1[r]);
    }
}

// ---------------------------------------------------------------------------
extern "C" void kernel_launch(void* const* d_in, const int* in_sizes, int n_in,
                              void* d_out, int out_size, void* d_ws, size_t ws_size,
                              hipStream_t stream) {
    const float* feat   = (const float*)d_in[0];   // [2,1024,8]
    const float* geo    = (const float*)d_in[1];   // [2,1024,3]
    const float* W      = (const float*)d_in[2];   // [32,8,8]
    const int*   n_norm = (const int*)  d_in[3];   // scalar 1024
    float* out = (float*)d_out;                    // [2,1024,8]

    half8* gws = (half8*)d_ws;                     // 2 MB

    g_kernel<<<(BATCH * NPTS * 64) / 256, 256, 0, stream>>>(feat, W, n_norm, gws, out);
    conv_mfma<<<BATCH * 16 * NCHUNK, 256, 0, stream>>>(geo, gws, out);
}